// Round 1
// baseline (1109.138 us; speedup 1.0000x reference)
//
#include <hip/hip_runtime.h>
#include <hip/hip_bf16.h>
#include <stdio.h>

// BNBQuantizedLinear: out[b,s,o] = sum_i x[b,s,i] * wd[o,i] + bias[o]
//   wd = (w - zp)*scale per contiguous group of 128 along the flat weight,
//   scale = (max-min)/15, zp = -min/scale  (affine transform, no rounding).
// Shapes: x [8192, 4096] f32, w [11008, 4096] f32, bias [11008] f32, out f32.
// Strategy: dequant w -> bf16 (ws), cast x -> bf16 (ws), then m97-structure
// 128x128 bf16 MFMA GEMM (16x16x32, global_load_lds width 16).

typedef unsigned short u16;
typedef __attribute__((ext_vector_type(8))) short short8;
typedef __attribute__((ext_vector_type(8))) unsigned short ushort8;
typedef __attribute__((ext_vector_type(4))) float f32x4;

constexpr int Mdim = 8192;
constexpr int Ndim = 11008;
constexpr int Kdim = 4096;

#define BM 128
#define BN 128
#define BK 32

__device__ __forceinline__ u16 f2bf(float f) {
  union { float f; unsigned u; } c; c.f = f;
  unsigned r = c.u + 0x7FFFu + ((c.u >> 16) & 1u);  // RTNE
  return (u16)(r >> 16);
}

// ---------------- kernel 1: group-dequant weight -> bf16 ----------------
// One wave (64 lanes) per group of 128; block = 4 waves.
__global__ __launch_bounds__(256) void k_dequant_w(const float* __restrict__ w,
                                                   u16* __restrict__ wb) {
  const int lane = threadIdx.x & 63;
  const long g = (long)blockIdx.x * 4 + (threadIdx.x >> 6);
  const long base = g * 128 + lane * 2;
  const float2 v = *(const float2*)(w + base);
  float mn = fminf(v.x, v.y), mx = fmaxf(v.x, v.y);
#pragma unroll
  for (int off = 32; off > 0; off >>= 1) {
    mn = fminf(mn, __shfl_xor(mn, off));
    mx = fmaxf(mx, __shfl_xor(mx, off));
  }
  const float scale = (mx - mn) / 15.0f;
  const float zp = -mn / scale;
  const u16 o0 = f2bf((v.x - zp) * scale);
  const u16 o1 = f2bf((v.y - zp) * scale);
  *(unsigned*)(wb + base) = (unsigned)o0 | ((unsigned)o1 << 16);
}

// ---------------- kernel 2: x f32 -> bf16 ----------------
__global__ __launch_bounds__(256) void k_cvt_x(const float* __restrict__ x,
                                               u16* __restrict__ xb) {
  const long i = ((long)blockIdx.x * 256 + threadIdx.x) * 8;
  const float4 v0 = *(const float4*)(x + i);
  const float4 v1 = *(const float4*)(x + i + 4);
  ushort8 o;
  o[0] = f2bf(v0.x); o[1] = f2bf(v0.y); o[2] = f2bf(v0.z); o[3] = f2bf(v0.w);
  o[4] = f2bf(v1.x); o[5] = f2bf(v1.y); o[6] = f2bf(v1.z); o[7] = f2bf(v1.w);
  *(ushort8*)(xb + i) = o;
}

// ---------------- kernel 3: bf16 GEMM, C = A * B^T + bias ----------------
// A [M,K] bf16 row-major, B [N,K] bf16 row-major (both K-contiguous).
// 128x128 tile, BK=32, 4 waves in 2x2, each wave 64x64 out (4x4 frags of
// 16x16x32 MFMA). Staging via global_load_lds dwordx4 (linear LDS layout).
__device__ __forceinline__ void async_ld16(const u16* g, u16* l) {
  __builtin_amdgcn_global_load_lds(
      (const __attribute__((address_space(1))) void*)g,
      (__attribute__((address_space(3))) void*)l, 16, 0, 0);
}

__global__ __launch_bounds__(256) void k_gemm(const u16* __restrict__ A,
                                              const u16* __restrict__ B,
                                              const float* __restrict__ bias,
                                              float* __restrict__ C) {
  __shared__ u16 As[BM * BK];   // 8 KB
  __shared__ u16 Bs[BN * BK];   // 8 KB

  const int t = threadIdx.x;
  const int wave = t >> 6;
  const int lane = t & 63;
  const int wm = wave >> 1;     // 2x2 wave grid over the 128x128 tile
  const int wn = wave & 1;
  const int bn0 = blockIdx.x * BN;
  const int bm0 = blockIdx.y * BM;
  const int r  = lane & 15;     // fragment row/col index
  const int kg = lane >> 4;     // k-group (8 elems each)

  // staging: thread t covers row (t>>2) of a 64-row half, 8 bf16 at col (t&3)*8
  const int g_row = t >> 2;
  const int g_c   = (t & 3) * 8;
  const u16* aptr = A + (size_t)(bm0 + g_row) * Kdim + g_c;
  const u16* bptr = B + (size_t)(bn0 + g_row) * Kdim + g_c;
  const size_t row64 = (size_t)64 * Kdim;
  // wave-uniform LDS bases (hw adds lane*16 bytes)
  u16* As_base = &As[wave * 512];
  u16* Bs_base = &Bs[wave * 512];

  f32x4 acc[4][4] = {};

  for (int k0 = 0; k0 < Kdim; k0 += BK) {
    async_ld16(aptr + k0,         As_base);
    async_ld16(aptr + k0 + row64, As_base + 2048);
    async_ld16(bptr + k0,         Bs_base);
    async_ld16(bptr + k0 + row64, Bs_base + 2048);
    __syncthreads();   // compiler drains vmcnt(0) before s_barrier

    short8 a[4], b[4];
#pragma unroll
    for (int m = 0; m < 4; ++m)
      a[m] = *(const short8*)&As[(wm * 64 + m * 16 + r) * BK + kg * 8];
#pragma unroll
    for (int n = 0; n < 4; ++n)
      b[n] = *(const short8*)&Bs[(wn * 64 + n * 16 + r) * BK + kg * 8];
#pragma unroll
    for (int m = 0; m < 4; ++m)
#pragma unroll
      for (int n = 0; n < 4; ++n)
        acc[m][n] = __builtin_amdgcn_mfma_f32_16x16x32_bf16(a[m], b[n], acc[m][n], 0, 0, 0);
    __syncthreads();
  }

  // epilogue: C/D layout col = lane&15, row = (lane>>4)*4 + j
#pragma unroll
  for (int n = 0; n < 4; ++n) {
    const int col = bn0 + wn * 64 + n * 16 + r;
    const float bv = bias[col];
#pragma unroll
    for (int m = 0; m < 4; ++m) {
      const int row0 = bm0 + wm * 64 + m * 16 + kg * 4;
#pragma unroll
      for (int j = 0; j < 4; ++j)
        C[(size_t)(row0 + j) * Ndim + col] = acc[m][n][j] + bv;
    }
  }
}

extern "C" void kernel_launch(void* const* d_in, const int* in_sizes, int n_in,
                              void* d_out, int out_size, void* d_ws, size_t ws_size,
                              hipStream_t stream) {
  const float* x    = (const float*)d_in[0];
  const float* w    = (const float*)d_in[1];
  const float* bias = (const float*)d_in[2];
  float* out = (float*)d_out;

  const size_t xb_elems = (size_t)Mdim * Kdim;   // 33,554,432
  const size_t wb_elems = (size_t)Ndim * Kdim;   // 45,088,768
  const size_t need = (xb_elems + wb_elems) * sizeof(u16);  // ~157 MB
  if (ws_size < need) {
    fprintf(stderr, "kernel_launch: ws too small (%zu < %zu)\n", ws_size, need);
    return;
  }
  u16* xb = (u16*)d_ws;
  u16* wb = xb + xb_elems;

  // 352,256 groups, 4 per block
  k_dequant_w<<<(int)(wb_elems / 128 / 4), 256, 0, stream>>>(w, wb);
  // 33.5M elems, 8 per thread
  k_cvt_x<<<(int)(xb_elems / (8 * 256)), 256, 0, stream>>>(x, xb);

  dim3 grid(Ndim / BN, Mdim / BM);  // (86, 64)
  k_gemm<<<grid, 256, 0, stream>>>(xb, wb, bias, out);
}

// Round 2
// 857.967 us; speedup vs baseline: 1.2928x; 1.2928x over previous
//
#include <hip/hip_runtime.h>
#include <hip/hip_bf16.h>
#include <stdio.h>

// BNBQuantizedLinear: out = x @ dequant(w)^T + bias
// x [8192,4096] f32, w [11008,4096] f32 (group-128 affine fake-quant), out f32.
// Round 2: 256x256 tile, BK=32, 4-deep LDS K-tile pipeline with counted vmcnt
// (T3/T4), XOR bank-swizzle via pre-swizzled global_load_lds source (T2, rule 21),
// setprio around MFMA clusters (T5), bijective XCD block swizzle (T1).

typedef unsigned short u16;
typedef __attribute__((ext_vector_type(8))) short short8;
typedef __attribute__((ext_vector_type(8))) unsigned short ushort8;
typedef __attribute__((ext_vector_type(4))) float f32x4;

constexpr int Mdim = 8192;
constexpr int Ndim = 11008;
constexpr int Kdim = 4096;

#define BK 32
#define NTILES 128          // Kdim / BK
#define TILE_ELEMS 8192     // 256 * 32 u16 per K-tile buffer (16 KB)

__device__ __forceinline__ u16 f2bf(float f) {
  union { float f; unsigned u; } c; c.f = f;
  unsigned r = c.u + 0x7FFFu + ((c.u >> 16) & 1u);  // RTNE
  return (u16)(r >> 16);
}

// ---------------- kernel 1: group-dequant weight -> bf16 ----------------
__global__ __launch_bounds__(256) void k_dequant_w(const float* __restrict__ w,
                                                   u16* __restrict__ wb) {
  const int lane = threadIdx.x & 63;
  const long g = (long)blockIdx.x * 4 + (threadIdx.x >> 6);
  const long base = g * 128 + lane * 2;
  const float2 v = *(const float2*)(w + base);
  float mn = fminf(v.x, v.y), mx = fmaxf(v.x, v.y);
#pragma unroll
  for (int off = 32; off > 0; off >>= 1) {
    mn = fminf(mn, __shfl_xor(mn, off));
    mx = fmaxf(mx, __shfl_xor(mx, off));
  }
  const float scale = (mx - mn) / 15.0f;
  const float zp = -mn / scale;
  const u16 o0 = f2bf((v.x - zp) * scale);
  const u16 o1 = f2bf((v.y - zp) * scale);
  *(unsigned*)(wb + base) = (unsigned)o0 | ((unsigned)o1 << 16);
}

// ---------------- kernel 2: x f32 -> bf16 ----------------
__global__ __launch_bounds__(256) void k_cvt_x(const float* __restrict__ x,
                                               u16* __restrict__ xb) {
  const long i = ((long)blockIdx.x * 256 + threadIdx.x) * 8;
  const float4 v0 = *(const float4*)(x + i);
  const float4 v1 = *(const float4*)(x + i + 4);
  ushort8 o;
  o[0] = f2bf(v0.x); o[1] = f2bf(v0.y); o[2] = f2bf(v0.z); o[3] = f2bf(v0.w);
  o[4] = f2bf(v1.x); o[5] = f2bf(v1.y); o[6] = f2bf(v1.z); o[7] = f2bf(v1.w);
  *(ushort8*)(xb + i) = o;
}

// ---------------- kernel 3: deep-pipelined 256x256 bf16 GEMM ----------------
__device__ __forceinline__ void async_ld16(const u16* g, u16* l) {
  __builtin_amdgcn_global_load_lds(
      (const __attribute__((address_space(1))) void*)g,
      (__attribute__((address_space(3))) void*)l, 16, 0, 0);
}

// LDS layout per K-tile buffer: [256 rows][32 cols] bf16, row = 64 B.
// Swizzle: 16B slot s within a row holds global k-slot  s ^ ((row>>1)&3)
//   -> read addr slot = kslot ^ ((row>>1)&3); rows 0..7 hit 8 distinct
//      bank-quads, rows 8..15 repeat (2-way = free, m136).
// global_load_lds dest stays LINEAR (rule 21); the SOURCE is pre-swizzled.

__global__ __launch_bounds__(512, 2) void k_gemm(const u16* __restrict__ A,
                                                 const u16* __restrict__ B,
                                                 const float* __restrict__ bias,
                                                 float* __restrict__ C) {
  __shared__ u16 As[4 * TILE_ELEMS];   // 64 KB: 4 K-tile buffers of A
  __shared__ u16 Bs[4 * TILE_ELEMS];   // 64 KB

  const int t = threadIdx.x;
  const int wave = t >> 6;        // 0..7
  const int lane = t & 63;
  const int wm = wave >> 2;       // wave grid 2(M) x 4(N); wave owns 128x64 out
  const int wn = wave & 3;
  const int r  = lane & 15;
  const int kg = lane >> 4;
  const int slot = kg ^ ((r >> 1) & 3);   // swizzled 16B-slot for ds_read

  // bijective XCD swizzle: 1376 workgroups, 1376/8 = 172 per XCD
  const int bid = blockIdx.x;
  const int wg = (bid & 7) * 172 + (bid >> 3);
  const int by = wg / 43;         // 0..31  (M tiles)
  const int bx = wg % 43;         // 0..42  (N tiles)
  const long bm0 = (long)by * 256;
  const long bn0 = (long)bx * 256;

  // staging: one issue = 512 thr x 16B = 8 KB = 128 rows; 2 issues per tile side.
  // thread t: row = t>>2, LDS slot = t&3; global source slot pre-XOR'd.
  const int s_row  = t >> 2;
  const int s_slot = (t & 3) ^ ((t >> 3) & 3);
  const u16* a_src = A + (bm0 + s_row) * Kdim + s_slot * 8;
  const u16* b_src = B + (bn0 + s_row) * Kdim + s_slot * 8;
  const int st_off = wave * 512;  // per-wave uniform LDS base within an issue

  // per-lane ds_read element offsets (within a K-tile buffer)
  const int a_roff = (wm * 128 + r) * 32 + slot * 8;  // + mf*512
  const int b_roff = (wn * 64  + r) * 32 + slot * 8;  // + nf*512

  f32x4 acc[8][4] = {};

#define STAGE_A(TAU, BUF) do {                                    \
    const u16* g_ = a_src + (size_t)(TAU) * 32;                   \
    u16* l_ = As + (BUF) * TILE_ELEMS + st_off;                   \
    async_ld16(g_, l_);                                           \
    async_ld16(g_ + (size_t)128 * Kdim, l_ + 4096);               \
  } while (0)
#define STAGE_B(TAU, BUF) do {                                    \
    const u16* g_ = b_src + (size_t)(TAU) * 32;                   \
    u16* l_ = Bs + (BUF) * TILE_ELEMS + st_off;                   \
    async_ld16(g_, l_);                                           \
    async_ld16(g_ + (size_t)128 * Kdim, l_ + 4096);               \
  } while (0)

  // prologue: stage tiles 0,1,2 (12 loads/wave in flight), land tile 0
  STAGE_A(0, 0); STAGE_B(0, 0);
  STAGE_A(1, 1); STAGE_B(1, 1);
  STAGE_A(2, 2); STAGE_B(2, 2);
  asm volatile("s_waitcnt vmcnt(8)" ::: "memory");
  __builtin_amdgcn_s_barrier();

  // One K-tile = 2 phases of 16 MFMA. Counted vmcnt at tile end, BEFORE the
  // trailing barrier (so after the barrier ALL waves' tile tau+1 loads landed).
#define KTILE(TAU, BUF, DO_STAGE, VMSTMT) do {                               \
    const u16* Ab_ = As + (BUF) * TILE_ELEMS;                                \
    const u16* Bb_ = Bs + (BUF) * TILE_ELEMS;                                \
    short8 af[4], bfr[4];                                                    \
    _Pragma("unroll")                                                        \
    for (int mf = 0; mf < 4; ++mf) af[mf] = *(const short8*)&Ab_[a_roff + mf*512]; \
    _Pragma("unroll")                                                        \
    for (int nf = 0; nf < 4; ++nf) bfr[nf] = *(const short8*)&Bb_[b_roff + nf*512]; \
    if (DO_STAGE) STAGE_A((TAU) + 3, ((BUF) + 3) & 3);                       \
    __builtin_amdgcn_s_barrier();                                            \
    asm volatile("s_waitcnt lgkmcnt(0)" ::: "memory");                       \
    __builtin_amdgcn_s_setprio(1);                                           \
    _Pragma("unroll")                                                        \
    for (int mf = 0; mf < 4; ++mf)                                           \
      _Pragma("unroll")                                                      \
      for (int nf = 0; nf < 4; ++nf)                                         \
        acc[mf][nf] = __builtin_amdgcn_mfma_f32_16x16x32_bf16(af[mf], bfr[nf], acc[mf][nf], 0, 0, 0); \
    __builtin_amdgcn_s_setprio(0);                                           \
    __builtin_amdgcn_s_barrier();                                            \
    _Pragma("unroll")                                                        \
    for (int mf = 0; mf < 4; ++mf) af[mf] = *(const short8*)&Ab_[a_roff + (mf + 4)*512]; \
    if (DO_STAGE) STAGE_B((TAU) + 3, ((BUF) + 3) & 3);                       \
    __builtin_amdgcn_s_barrier();                                            \
    asm volatile("s_waitcnt lgkmcnt(0)" ::: "memory");                       \
    __builtin_amdgcn_s_setprio(1);                                           \
    _Pragma("unroll")                                                        \
    for (int mf = 0; mf < 4; ++mf)                                           \
      _Pragma("unroll")                                                      \
      for (int nf = 0; nf < 4; ++nf)                                         \
        acc[mf + 4][nf] = __builtin_amdgcn_mfma_f32_16x16x32_bf16(af[mf], bfr[nf], acc[mf + 4][nf], 0, 0, 0); \
    __builtin_amdgcn_s_setprio(0);                                           \
    VMSTMT;                                                                  \
    __builtin_amdgcn_s_barrier();                                            \
  } while (0)

#define VM8 asm volatile("s_waitcnt vmcnt(8)" ::: "memory")
#define VM4 asm volatile("s_waitcnt vmcnt(4)" ::: "memory")
#define VM0 asm volatile("s_waitcnt vmcnt(0)" ::: "memory")

  for (int tau = 0; tau < NTILES - 4; tau += 4) {
    KTILE(tau + 0, 0, 1, VM8);
    KTILE(tau + 1, 1, 1, VM8);
    KTILE(tau + 2, 2, 1, VM8);
    KTILE(tau + 3, 3, 1, VM8);
  }
  KTILE(NTILES - 4, 0, 1, VM8);   // stages tile 127
  KTILE(NTILES - 3, 1, 0, VM4);
  KTILE(NTILES - 2, 2, 0, VM0);
  KTILE(NTILES - 1, 3, 0, (void)0);

  // epilogue: C/D layout col = lane&15, row = (lane>>4)*4 + j
#pragma unroll
  for (int nf = 0; nf < 4; ++nf) {
    const long col = bn0 + wn * 64 + nf * 16 + r;
    const float bv = bias[col];
#pragma unroll
    for (int mf = 0; mf < 8; ++mf) {
      const long row0 = bm0 + wm * 128 + mf * 16 + kg * 4;
#pragma unroll
      for (int j = 0; j < 4; ++j)
        C[(row0 + j) * Ndim + col] = acc[mf][nf][j] + bv;
    }
  }
}

extern "C" void kernel_launch(void* const* d_in, const int* in_sizes, int n_in,
                              void* d_out, int out_size, void* d_ws, size_t ws_size,
                              hipStream_t stream) {
  const float* x    = (const float*)d_in[0];
  const float* w    = (const float*)d_in[1];
  const float* bias = (const float*)d_in[2];
  float* out = (float*)d_out;

  const size_t xb_elems = (size_t)Mdim * Kdim;
  const size_t wb_elems = (size_t)Ndim * Kdim;
  const size_t need = (xb_elems + wb_elems) * sizeof(u16);
  if (ws_size < need) {
    fprintf(stderr, "kernel_launch: ws too small (%zu < %zu)\n", ws_size, need);
    return;
  }
  u16* xb = (u16*)d_ws;
  u16* wb = xb + xb_elems;

  k_dequant_w<<<(int)(wb_elems / 128 / 4), 256, 0, stream>>>(w, wb);
  k_cvt_x<<<(int)(xb_elems / (8 * 256)), 256, 0, stream>>>(x, xb);

  // grid: 43 N-tiles x 32 M-tiles = 1376 blocks (divisible by 8 XCDs)
  k_gemm<<<(Ndim / 256) * (Mdim / 256), 512, 0, stream>>>(xb, wb, bias, out);
}